// Round 4
// baseline (493.525 us; speedup 1.0000x reference)
//
#include <hip/hip_runtime.h>

// Fixed problem sizes
#define HID 2048
#define SEQL 4096
#define CHUNK 2048
#define NHEADS 8
#define NKVH 4
#define HDIM 256

typedef __bf16 bf16x4 __attribute__((ext_vector_type(4)));
typedef __bf16 bf16x8 __attribute__((ext_vector_type(8)));
typedef float f32x4 __attribute__((ext_vector_type(4)));
typedef _Float16 f16x4 __attribute__((ext_vector_type(4)));
typedef __attribute__((address_space(1))) unsigned int* as1_u32;
typedef __attribute__((address_space(3))) unsigned int* as3_u32;

// async global->LDS, 16B per lane; LDS dest = uniform base + lane*16
__device__ __forceinline__ void load_lds16(const __bf16* g, __bf16* l) {
  __builtin_amdgcn_global_load_lds((as1_u32)g, (as3_u32)l, 16, 0, 0);
}

// ---------- fp32 -> bf16 convert (4 elems/thread) ----------
__global__ void cvt_bf16_kernel(const float* __restrict__ X, __bf16* __restrict__ Y) {
  int i = blockIdx.x * blockDim.x + threadIdx.x;
  const float4* xv = (const float4*)X;
  float4 v = xv[i];
  bf16x4 o;
  o[0] = (__bf16)v.x; o[1] = (__bf16)v.y; o[2] = (__bf16)v.z; o[3] = (__bf16)v.w;
  *(bf16x4*)(Y + i * 4) = o;
}

// ---------- W (RxC f32, row-major) -> WT (CxR bf16), WT row stride = R ----------
__global__ void transpose_cvt_kernel(const float* __restrict__ W, __bf16* __restrict__ WT,
                                     int R, int C) {
  __shared__ float tile[64][65];
  int r0 = blockIdx.y * 64, c0 = blockIdx.x * 64;
  for (int i = threadIdx.x; i < 4096; i += 256) {
    int r = i >> 6, c = i & 63;
    tile[r][c] = W[(r0 + r) * C + c0 + c];
  }
  __syncthreads();
  for (int i = threadIdx.x; i < 4096; i += 256) {
    int c = i >> 6, r = i & 63;
    WT[(c0 + c) * R + r0 + r] = (__bf16)tile[r][c];
  }
}

// ---------- C(MxN) = A(MxK) @ B^T(NxK), bf16 in, fp32 acc ----------
// m97 pattern; tile 128 x (NI*32); NI=4 -> 128x128, NI=2 -> 128x64
template <int NI, bool F32OUT>
__global__ __launch_bounds__(256, 2) void gemm_bt_kernel(
    const __bf16* __restrict__ A, const __bf16* __restrict__ B,
    void* __restrict__ Cv, int M, int N, int Kd) {
  constexpr int BN = NI * 32;
  __shared__ __bf16 Asm[128 * 32];
  __shared__ __bf16 Bsm[BN * 32];
  const int tid = threadIdx.x;
  const int lane = tid & 63, wave = tid >> 6;
  const int quad = lane >> 4, l15 = lane & 15;
  const int m0 = blockIdx.x * 128, n0 = blockIdx.y * BN;
  const int wm = (wave & 1) * 64, wn = (wave >> 1) * (NI * 16);
  f32x4 acc[4][NI];
#pragma unroll
  for (int i = 0; i < 4; i++)
#pragma unroll
    for (int j = 0; j < NI; j++) acc[i][j] = (f32x4){0.f, 0.f, 0.f, 0.f};

  const int rA = lane >> 2, cA = (lane & 3) * 8;

  for (int k0 = 0; k0 < Kd; k0 += 32) {
#pragma unroll
    for (int c = wave; c < 8; c += 4)
      load_lds16(A + (size_t)(m0 + c * 16 + rA) * Kd + k0 + cA, Asm + c * 512);
#pragma unroll
    for (int c = wave; c < BN / 16; c += 4)
      load_lds16(B + (size_t)(n0 + c * 16 + rA) * Kd + k0 + cA, Bsm + c * 512);
    __syncthreads();
    bf16x8 af[4], bfr[NI];
#pragma unroll
    for (int i = 0; i < 4; i++)
      af[i] = *(const bf16x8*)(Asm + (wm + i * 16 + l15) * 32 + quad * 8);
#pragma unroll
    for (int i = 0; i < NI; i++)
      bfr[i] = *(const bf16x8*)(Bsm + (wn + i * 16 + l15) * 32 + quad * 8);
#pragma unroll
    for (int mi = 0; mi < 4; mi++)
#pragma unroll
      for (int ni = 0; ni < NI; ni++)
        acc[mi][ni] = __builtin_amdgcn_mfma_f32_16x16x32_bf16(af[mi], bfr[ni], acc[mi][ni], 0, 0, 0);
    __syncthreads();
  }
#pragma unroll
  for (int mi = 0; mi < 4; mi++) {
    int r = m0 + wm + mi * 16 + quad * 4;
#pragma unroll
    for (int ni = 0; ni < NI; ni++) {
      int cc = n0 + wn + ni * 16 + l15;
#pragma unroll
      for (int j = 0; j < 4; j++) {
        if (F32OUT)
          ((float*)Cv)[(size_t)(r + j) * N + cc] = acc[mi][ni][j];
        else
          ((__bf16*)Cv)[(size_t)(r + j) * N + cc] = (__bf16)acc[mi][ni][j];
      }
    }
  }
}

// ---------- RMSNorm (+RoPE) per (token, head); one wave per row ----------
// MODE 0: Q (rope, pos=t+2048, H=8, in-place, prescaled by 2^-4)
// MODE 1: K (rope, pos=t,      H=4, in-place)
// MODE 2: V (norm only, H=4, write transposed VT[h][d][t])
template <int MODE>
__global__ void norm_rope_kernel(__bf16* __restrict__ X, int RS, __bf16* __restrict__ VT,
                                 const float* __restrict__ cosb, const float* __restrict__ sinb,
                                 const float* __restrict__ w) {
  const int gw = (blockIdx.x * 256 + threadIdx.x) >> 6;
  const int lane = threadIdx.x & 63;
  const int H = (MODE == 0) ? 8 : 4;
  const int t = gw / H, h = gw % H;
  __bf16* row = X + (size_t)t * RS + h * 256;
  const int d0 = lane * 4;
  bf16x4 rv = *(const bf16x4*)(row + d0);
  float x[4];
  float ss = 0.f;
#pragma unroll
  for (int j = 0; j < 4; j++) { x[j] = (float)rv[j]; ss += x[j] * x[j]; }
#pragma unroll
  for (int off = 1; off < 64; off <<= 1) ss += __shfl_xor(ss, off);
  float scale = rsqrtf(ss * (1.f / 256.f) + 1e-6f);
  float n[4];
#pragma unroll
  for (int j = 0; j < 4; j++) n[j] = x[j] * scale * (1.f + w[d0 + j]);
  if (MODE < 2) {
    const int pos = t + (MODE == 0 ? 2048 : 0);
    const float* cp = cosb + pos * 256 + d0;
    const float* sp = sinb + pos * 256 + d0;
    bf16x4 ov;
#pragma unroll
    for (int j = 0; j < 4; j++) {
      float other = __shfl_xor(n[j], 32);           // d and d^128 live in lane^32
      float rot = (lane < 32) ? -other : other;     // rotate_half sign
      float r = n[j] * cp[j] + rot * sp[j];
      if (MODE == 0) r *= 0.0625f;                  // fold HEAD_DIM^-0.5 (exact pow2)
      ov[j] = (__bf16)r;
    }
    *(bf16x4*)(row + d0) = ov;
  } else {
#pragma unroll
    for (int j = 0; j < 4; j++)
      VT[(size_t)h * (256 * 4096) + (size_t)(d0 + j) * 4096 + t] = (__bf16)n[j];
  }
}

// ---------- flash attention, fixed softmax max (softcap bounds logits to +-50) ----------
// grid 512: h = bx&7 (XCD-pinned), sp = (bx>>3)&3 (KV split x4), qt = bx>>5 (128-q tiles).
// 4 waves x 32 q-rows (2 A-frags each). Double-buffered K/V LDS.
// Partial O is NORMALIZED per split (O_i/l_i, O(1) magnitude -> safe in fp16);
// the tiny softmax exponent lives entirely in the fp32 l_i. Merge does the
// l-weighted average. (R3 bug: unnormalized partials ~1e-19 underflow fp16.)
__global__ __launch_bounds__(256, 2) void attn_kernel(
    const __bf16* __restrict__ Q,   // [2048][8*256] post norm+rope, prescaled 2^-4
    const __bf16* __restrict__ K,   // [4096][2048] cols 0..1023 = K heads (post norm+rope)
    const __bf16* __restrict__ VT,  // [4][256][4096] post norm, transposed
    _Float16* __restrict__ Op,      // [4][2048][2048] normalized partial O (fp16)
    float* __restrict__ Lp) {       // [4][2048][8]    partial l (fp32)
  __shared__ __bf16 Ksm[2][8][32][32];  // 32 KB  [buf][d-panel][key][d]
  __shared__ __bf16 Vsm[2][256][32];    // 32 KB  [buf][d][key]
  __shared__ __bf16 Pex[4][32][40];     // 10 KB  per-wave P C->A exchange
  const int tid = threadIdx.x;
  const int lane = tid & 63, wave = tid >> 6;
  const int quad = lane >> 4, l15 = lane & 15;
  const int b = blockIdx.x;
  const int h = b & 7, sp = (b >> 3) & 3, qt = b >> 5;
  const int kvh = h >> 1;

  const int T = 68 + 4 * qt;            // total 32-key steps; T % 4 == 0 always
  const int nst = T >> 2;
  const int s0 = sp * nst;

  bf16x8 qf[2][8];
#pragma unroll
  for (int r = 0; r < 2; r++) {
    const __bf16* qp = Q + (size_t)(qt * 128 + wave * 32 + r * 16 + l15) * 2048 + h * 256 + quad * 8;
#pragma unroll
    for (int s = 0; s < 8; s++) qf[r][s] = *(const bf16x8*)(qp + s * 32);
  }
  f32x4 o[2][16];
#pragma unroll
  for (int r = 0; r < 2; r++)
#pragma unroll
    for (int i = 0; i < 16; i++) o[r][i] = (f32x4){0.f, 0.f, 0.f, 0.f};
  float rs[2][4] = {{0.f, 0.f, 0.f, 0.f}, {0.f, 0.f, 0.f, 0.f}};

  const __bf16* Kb = K + kvh * 256;
  const __bf16* Vb = VT + (size_t)kvh * (256 * 4096);
  const int rA = lane >> 2, cA = (lane & 3) * 8;
  const int qbase = 2048 + qt * 128 + wave * 32 + quad * 4;  // + r*16 + j

  // stage step s0 into buf 0
  {
    const int t0 = s0 * 32;
#pragma unroll
    for (int ch = 0; ch < 4; ch++) {
      int cc = wave + ch * 4;
      int s = cc >> 1, hf = cc & 1;
      load_lds16(Kb + (size_t)(t0 + hf * 16 + rA) * 2048 + s * 32 + cA, &Ksm[0][s][hf * 16][0]);
      load_lds16(Vb + (size_t)(cc * 16 + rA) * 4096 + t0 + cA, &Vsm[0][cc * 16][0]);
    }
  }

  for (int i = 0; i < nst; i++) {
    const int buf = i & 1;
    const int t0 = (s0 + i) * 32;
    __syncthreads();  // buf ready; all waves done with other buf
    if (i + 1 < nst) {
      const int t1 = t0 + 32;
#pragma unroll
      for (int ch = 0; ch < 4; ch++) {
        int cc = wave + ch * 4;
        int s = cc >> 1, hf = cc & 1;
        load_lds16(Kb + (size_t)(t1 + hf * 16 + rA) * 2048 + s * 32 + cA, &Ksm[buf ^ 1][s][hf * 16][0]);
        load_lds16(Vb + (size_t)(cc * 16 + rA) * 4096 + t1 + cA, &Vsm[buf ^ 1][cc * 16][0]);
      }
    }

    // S = Q K^T : 32q x 32k per wave; each K B-frag feeds 2 MFMAs (r=0,1)
    f32x4 s4[2][2];
    s4[0][0] = (f32x4){0.f, 0.f, 0.f, 0.f};
    s4[0][1] = s4[0][0]; s4[1][0] = s4[0][0]; s4[1][1] = s4[0][0];
#pragma unroll
    for (int s = 0; s < 8; s++) {
      bf16x8 b0 = *(const bf16x8*)(&Ksm[buf][s][l15][quad * 8]);
      bf16x8 b1 = *(const bf16x8*)(&Ksm[buf][s][16 + l15][quad * 8]);
      s4[0][0] = __builtin_amdgcn_mfma_f32_16x16x32_bf16(qf[0][s], b0, s4[0][0], 0, 0, 0);
      s4[0][1] = __builtin_amdgcn_mfma_f32_16x16x32_bf16(qf[0][s], b1, s4[0][1], 0, 0, 0);
      s4[1][0] = __builtin_amdgcn_mfma_f32_16x16x32_bf16(qf[1][s], b0, s4[1][0], 0, 0, 0);
      s4[1][1] = __builtin_amdgcn_mfma_f32_16x16x32_bf16(qf[1][s], b1, s4[1][1], 0, 0, 0);
    }

    // p = exp(50*tanh(v/50) - 50) = exp(-100/(e^{0.04v}+1)); max pinned at 50.
    const bool mk = (sp == 3) && (i >= nst - 4);
#pragma unroll
    for (int r = 0; r < 2; r++)
#pragma unroll
      for (int nt = 0; nt < 2; nt++) {
        const int key = t0 + nt * 16 + l15;
#pragma unroll
        for (int j = 0; j < 4; j++) {
          float v = s4[r][nt][j];
          float e = __expf(v * 0.04f);
          float p = __expf(-100.f / (e + 1.f));
          if (mk && key > qbase + r * 16 + j) p = 0.f;
          s4[r][nt][j] = p;
          rs[r][j] += p;  // per-lane partial; cross-lane reduce at end
        }
      }

    // P: C-layout -> LDS -> A-layout (per-wave slab)
#pragma unroll
    for (int r = 0; r < 2; r++)
#pragma unroll
      for (int nt = 0; nt < 2; nt++)
#pragma unroll
        for (int j = 0; j < 4; j++)
          Pex[wave][r * 16 + quad * 4 + j][nt * 16 + l15] = (__bf16)s4[r][nt][j];

    bf16x8 pf0 = *(const bf16x8*)(&Pex[wave][l15][quad * 8]);
    bf16x8 pf1 = *(const bf16x8*)(&Pex[wave][16 + l15][quad * 8]);
#pragma unroll
    for (int d = 0; d < 16; d++) {
      bf16x8 vf = *(const bf16x8*)(&Vsm[buf][d * 16 + l15][quad * 8]);
      o[0][d] = __builtin_amdgcn_mfma_f32_16x16x32_bf16(pf0, vf, o[0][d], 0, 0, 0);
      o[1][d] = __builtin_amdgcn_mfma_f32_16x16x32_bf16(pf1, vf, o[1][d], 0, 0, 0);
    }
  }

  // reduce row-sums over the 16 key-columns held across l15 lanes
#pragma unroll
  for (int off = 1; off < 16; off <<= 1)
#pragma unroll
    for (int r = 0; r < 2; r++)
#pragma unroll
      for (int j = 0; j < 4; j++) rs[r][j] += __shfl_xor(rs[r][j], off);

  _Float16* Os = Op + (size_t)sp * (2048 * 2048);
  float* Ls = Lp + sp * (2048 * 8);
#pragma unroll
  for (int r = 0; r < 2; r++) {
    float inv[4];
#pragma unroll
    for (int j = 0; j < 4; j++)
      inv[j] = rs[r][j] > 0.f ? 1.f / rs[r][j] : 0.f;
    const int trow = qt * 128 + wave * 32 + r * 16 + quad * 4;
#pragma unroll
    for (int d = 0; d < 16; d++) {
      const int col = h * 256 + d * 16 + l15;
#pragma unroll
      for (int j = 0; j < 4; j++)
        Os[(size_t)(trow + j) * 2048 + col] = (_Float16)(o[r][d][j] * inv[j]);
    }
    if (l15 == 0) {
#pragma unroll
      for (int j = 0; j < 4; j++) Ls[(trow + j) * 8 + h] = rs[r][j];
    }
  }
}

// ---------- merge: O = sum(l_i * Onorm_i) / sum(l_i) ----------
__global__ void merge_kernel(const _Float16* __restrict__ Op, const float* __restrict__ Lp,
                             __bf16* __restrict__ AO) {
  int f = (blockIdx.x * 256 + threadIdx.x) * 4;
  int q = f >> 11, col = f & 2047, h = col >> 8;
  float lsum = 0.f;
  float acc[4] = {0.f, 0.f, 0.f, 0.f};
#pragma unroll
  for (int s = 0; s < 4; s++) {
    float l = Lp[s * (2048 * 8) + q * 8 + h];
    lsum += l;
    f16x4 v = *(const f16x4*)(Op + (size_t)s * (2048 * 2048) + f);
#pragma unroll
    for (int j = 0; j < 4; j++) acc[j] += l * (float)v[j];
  }
  float inv = 1.f / lsum;
  bf16x4 o;
#pragma unroll
  for (int j = 0; j < 4; j++) o[j] = (__bf16)(acc[j] * inv);
  *(bf16x4*)(AO + f) = o;
}

extern "C" void kernel_launch(void* const* d_in, const int* in_sizes, int n_in,
                              void* d_out, int out_size, void* d_ws, size_t ws_size,
                              hipStream_t stream) {
  const float* hidden = (const float*)d_in[0];
  const float* cosb = (const float*)d_in[1];
  const float* sinb = (const float*)d_in[2];
  // d_in[3] attention_mask: causal, reproduced analytically
  const float* wq = (const float*)d_in[4];
  const float* wk = (const float*)d_in[5];
  const float* wv = (const float*)d_in[6];
  const float* wo = (const float*)d_in[7];
  const float* qw = (const float*)d_in[8];
  const float* kw = (const float*)d_in[9];
  const float* vw = (const float*)d_in[10];
  float* outp = (float*)d_out;

  char* p = (char*)d_ws;
  __bf16* Xb = (__bf16*)p;   p += (size_t)SEQL * HID * 2;       // 16 MB (dead after GEMMs)
  __bf16* WQT = (__bf16*)p;  p += (size_t)2048 * 2048 * 2;      // 8 MB  (dead after Q GEMM)
  __bf16* WKVT = (__bf16*)p; p += (size_t)2048 * 2048 * 2;      // 8 MB  (dead after KV GEMM)
  __bf16* WOT = (__bf16*)p;  p += (size_t)2048 * 2048 * 2;      // 8 MB
  __bf16* Qp = (__bf16*)p;   p += (size_t)2048 * 2048 * 2;      // 8 MB
  __bf16* KVp = (__bf16*)p;  p += (size_t)4096 * 2048 * 2;      // 16 MB
  __bf16* VT = (__bf16*)p;   p += (size_t)4 * 256 * 4096 * 2;   // 8 MB
  __bf16* AO = (__bf16*)p;   p += (size_t)2048 * 2048 * 2;      // 8 MB
  float* Lpart = (float*)p;  p += (size_t)4 * 2048 * 8 * 4;     // 256 KB (total ~80.3 MB)
  // fp16 normalized partial O (4 x 8 MB = 32 MB) overlays the dead
  // Xb(16)+WQT(8)+WKVT(8) regions (contiguous, end exactly at WOT).
  _Float16* Opart = (_Float16*)Xb;

  // 1) convert inputs / weights to bf16 (weights transposed to NxK)
  cvt_bf16_kernel<<<8192, 256, 0, stream>>>(hidden, Xb);
  transpose_cvt_kernel<<<dim3(32, 32), 256, 0, stream>>>(wq, WQT, 2048, 2048);
  transpose_cvt_kernel<<<dim3(16, 32), 256, 0, stream>>>(wk, WKVT, 2048, 1024);
  transpose_cvt_kernel<<<dim3(16, 32), 256, 0, stream>>>(wv, WKVT + (size_t)1024 * 2048, 2048, 1024);
  transpose_cvt_kernel<<<dim3(32, 32), 256, 0, stream>>>(wo, WOT, 2048, 2048);

  // 2) projections: Q (128x64 tiles, 512 blocks), fused KV (128x128, 512 blocks)
  gemm_bt_kernel<2, false><<<dim3(16, 32), 256, 0, stream>>>(Xb + (size_t)2048 * 2048, WQT, Qp, 2048, 2048, 2048);
  gemm_bt_kernel<4, false><<<dim3(32, 16), 256, 0, stream>>>(Xb, WKVT, KVp, 4096, 2048, 2048);

  // 3) RMSNorm (+RoPE); Q prescaled by 2^-4; V transposed for PV fragments
  norm_rope_kernel<0><<<4096, 256, 0, stream>>>(Qp, 2048, nullptr, cosb, sinb, qw);
  norm_rope_kernel<1><<<4096, 256, 0, stream>>>(KVp, 2048, nullptr, cosb, sinb, kw);
  norm_rope_kernel<2><<<4096, 256, 0, stream>>>(KVp + 1024, 2048, VT, cosb, sinb, vw);

  // 4) flash attention, KV-split x4, 32 q-rows/wave, normalized fp16 partials
  attn_kernel<<<512, 256, 0, stream>>>(Qp, KVp, VT, Opart, Lpart);
  merge_kernel<<<4096, 256, 0, stream>>>(Opart, Lpart, AO);

  // 5) output projection -> fp32 (128x64 tiles, 512 blocks)
  gemm_bt_kernel<2, true><<<dim3(16, 32), 256, 0, stream>>>(AO, WOT, outp, 2048, 2048, 2048);
}

// Round 5
// 453.466 us; speedup vs baseline: 1.0883x; 1.0883x over previous
//
#include <hip/hip_runtime.h>

// Fixed problem sizes
#define HID 2048
#define SEQL 4096
#define CHUNK 2048
#define NHEADS 8
#define NKVH 4
#define HDIM 256

typedef __bf16 bf16x4 __attribute__((ext_vector_type(4)));
typedef __bf16 bf16x8 __attribute__((ext_vector_type(8)));
typedef float f32x4 __attribute__((ext_vector_type(4)));
typedef _Float16 f16x4 __attribute__((ext_vector_type(4)));
typedef __attribute__((address_space(1))) unsigned int* as1_u32;
typedef __attribute__((address_space(3))) unsigned int* as3_u32;

// async global->LDS, 16B per lane; LDS dest = uniform base + lane*16
__device__ __forceinline__ void load_lds16(const __bf16* g, __bf16* l) {
  __builtin_amdgcn_global_load_lds((as1_u32)g, (as3_u32)l, 16, 0, 0);
}

// ---------- fp32 -> bf16 convert (4 elems/thread) ----------
__global__ void cvt_bf16_kernel(const float* __restrict__ X, __bf16* __restrict__ Y) {
  int i = blockIdx.x * blockDim.x + threadIdx.x;
  const float4* xv = (const float4*)X;
  float4 v = xv[i];
  bf16x4 o;
  o[0] = (__bf16)v.x; o[1] = (__bf16)v.y; o[2] = (__bf16)v.z; o[3] = (__bf16)v.w;
  *(bf16x4*)(Y + i * 4) = o;
}

// ---------- W (RxC f32, row-major) -> WT (CxR bf16), WT row stride = R ----------
__global__ void transpose_cvt_kernel(const float* __restrict__ W, __bf16* __restrict__ WT,
                                     int R, int C) {
  __shared__ float tile[64][65];
  int r0 = blockIdx.y * 64, c0 = blockIdx.x * 64;
  for (int i = threadIdx.x; i < 4096; i += 256) {
    int r = i >> 6, c = i & 63;
    tile[r][c] = W[(r0 + r) * C + c0 + c];
  }
  __syncthreads();
  for (int i = threadIdx.x; i < 4096; i += 256) {
    int c = i >> 6, r = i & 63;
    WT[(c0 + c) * R + r0 + r] = (__bf16)tile[r][c];
  }
}

// ---------- fused Q + KV projection: 768 blocks, all 128x128 tiles, 3 blocks/CU ----------
// b in [0,512): KV GEMM  KVp[4096,2048] = Xb[4096,2048] @ WKVT^T
// b in [512,768): Q GEMM Qp[2048,2048]  = Xb[rows 2048..4095] @ WQT^T
__global__ __launch_bounds__(256, 3) void proj_kernel(
    const __bf16* __restrict__ Xb, const __bf16* __restrict__ WQT,
    const __bf16* __restrict__ WKVT, __bf16* __restrict__ Qp, __bf16* __restrict__ KVp) {
  __shared__ __bf16 Asm[128 * 32];
  __shared__ __bf16 Bsm[128 * 32];
  const int tid = threadIdx.x;
  const int lane = tid & 63, wave = tid >> 6;
  const int quad = lane >> 4, l15 = lane & 15;
  const int b = blockIdx.x;
  const __bf16 *A, *B;
  __bf16* C;
  int m0, n0;
  if (b < 512) {
    A = Xb; B = WKVT; C = KVp;
    m0 = (b & 31) * 128; n0 = (b >> 5) * 128;
  } else {
    int q = b - 512;
    A = Xb + (size_t)2048 * 2048; B = WQT; C = Qp;
    m0 = (q & 15) * 128; n0 = (q >> 4) * 128;
  }
  const int wm = (wave & 1) * 64, wn = (wave >> 1) * 64;
  f32x4 acc[4][4];
#pragma unroll
  for (int i = 0; i < 4; i++)
#pragma unroll
    for (int j = 0; j < 4; j++) acc[i][j] = (f32x4){0.f, 0.f, 0.f, 0.f};

  const int rA = lane >> 2, cA = (lane & 3) * 8;

  for (int k0 = 0; k0 < 2048; k0 += 32) {
#pragma unroll
    for (int c = wave; c < 8; c += 4) {
      load_lds16(A + (size_t)(m0 + c * 16 + rA) * 2048 + k0 + cA, Asm + c * 512);
      load_lds16(B + (size_t)(n0 + c * 16 + rA) * 2048 + k0 + cA, Bsm + c * 512);
    }
    __syncthreads();
    bf16x8 af[4], bfr[4];
#pragma unroll
    for (int i = 0; i < 4; i++) {
      af[i] = *(const bf16x8*)(Asm + (wm + i * 16 + l15) * 32 + quad * 8);
      bfr[i] = *(const bf16x8*)(Bsm + (wn + i * 16 + l15) * 32 + quad * 8);
    }
#pragma unroll
    for (int mi = 0; mi < 4; mi++)
#pragma unroll
      for (int ni = 0; ni < 4; ni++)
        acc[mi][ni] = __builtin_amdgcn_mfma_f32_16x16x32_bf16(af[mi], bfr[ni], acc[mi][ni], 0, 0, 0);
    __syncthreads();
  }
#pragma unroll
  for (int mi = 0; mi < 4; mi++) {
    int r = m0 + wm + mi * 16 + quad * 4;
#pragma unroll
    for (int ni = 0; ni < 4; ni++) {
      int cc = n0 + wn + ni * 16 + l15;
#pragma unroll
      for (int j = 0; j < 4; j++)
        C[(size_t)(r + j) * 2048 + cc] = (__bf16)acc[mi][ni][j];
    }
  }
}

// ---------- C(MxN) = A(MxK) @ B^T(NxK), bf16 in, fp32 acc (output projection) ----------
template <int NI, bool F32OUT>
__global__ __launch_bounds__(256, 2) void gemm_bt_kernel(
    const __bf16* __restrict__ A, const __bf16* __restrict__ B,
    void* __restrict__ Cv, int M, int N, int Kd) {
  constexpr int BN = NI * 32;
  __shared__ __bf16 Asm[128 * 32];
  __shared__ __bf16 Bsm[BN * 32];
  const int tid = threadIdx.x;
  const int lane = tid & 63, wave = tid >> 6;
  const int quad = lane >> 4, l15 = lane & 15;
  const int m0 = blockIdx.x * 128, n0 = blockIdx.y * BN;
  const int wm = (wave & 1) * 64, wn = (wave >> 1) * (NI * 16);
  f32x4 acc[4][NI];
#pragma unroll
  for (int i = 0; i < 4; i++)
#pragma unroll
    for (int j = 0; j < NI; j++) acc[i][j] = (f32x4){0.f, 0.f, 0.f, 0.f};

  const int rA = lane >> 2, cA = (lane & 3) * 8;

  for (int k0 = 0; k0 < Kd; k0 += 32) {
#pragma unroll
    for (int c = wave; c < 8; c += 4)
      load_lds16(A + (size_t)(m0 + c * 16 + rA) * Kd + k0 + cA, Asm + c * 512);
#pragma unroll
    for (int c = wave; c < BN / 16; c += 4)
      load_lds16(B + (size_t)(n0 + c * 16 + rA) * Kd + k0 + cA, Bsm + c * 512);
    __syncthreads();
    bf16x8 af[4], bfr[NI];
#pragma unroll
    for (int i = 0; i < 4; i++)
      af[i] = *(const bf16x8*)(Asm + (wm + i * 16 + l15) * 32 + quad * 8);
#pragma unroll
    for (int i = 0; i < NI; i++)
      bfr[i] = *(const bf16x8*)(Bsm + (wn + i * 16 + l15) * 32 + quad * 8);
#pragma unroll
    for (int mi = 0; mi < 4; mi++)
#pragma unroll
      for (int ni = 0; ni < NI; ni++)
        acc[mi][ni] = __builtin_amdgcn_mfma_f32_16x16x32_bf16(af[mi], bfr[ni], acc[mi][ni], 0, 0, 0);
    __syncthreads();
  }
#pragma unroll
  for (int mi = 0; mi < 4; mi++) {
    int r = m0 + wm + mi * 16 + quad * 4;
#pragma unroll
    for (int ni = 0; ni < NI; ni++) {
      int cc = n0 + wn + ni * 16 + l15;
#pragma unroll
      for (int j = 0; j < 4; j++) {
        if (F32OUT)
          ((float*)Cv)[(size_t)(r + j) * N + cc] = acc[mi][ni][j];
        else
          ((__bf16*)Cv)[(size_t)(r + j) * N + cc] = (__bf16)acc[mi][ni][j];
      }
    }
  }
}

// ---------- RMSNorm (+RoPE) per (token, head); one wave per row ----------
// MODE 0: Q (rope, pos=t+2048, H=8, in-place, prescaled by 2^-4)
// MODE 1: K (rope, pos=t,      H=4, in-place)
// MODE 2: V (norm only, H=4, write transposed VT[h][d][t])
template <int MODE>
__global__ void norm_rope_kernel(__bf16* __restrict__ X, int RS, __bf16* __restrict__ VT,
                                 const float* __restrict__ cosb, const float* __restrict__ sinb,
                                 const float* __restrict__ w) {
  const int gw = (blockIdx.x * 256 + threadIdx.x) >> 6;
  const int lane = threadIdx.x & 63;
  const int H = (MODE == 0) ? 8 : 4;
  const int t = gw / H, h = gw % H;
  __bf16* row = X + (size_t)t * RS + h * 256;
  const int d0 = lane * 4;
  bf16x4 rv = *(const bf16x4*)(row + d0);
  float x[4];
  float ss = 0.f;
#pragma unroll
  for (int j = 0; j < 4; j++) { x[j] = (float)rv[j]; ss += x[j] * x[j]; }
#pragma unroll
  for (int off = 1; off < 64; off <<= 1) ss += __shfl_xor(ss, off);
  float scale = rsqrtf(ss * (1.f / 256.f) + 1e-6f);
  float n[4];
#pragma unroll
  for (int j = 0; j < 4; j++) n[j] = x[j] * scale * (1.f + w[d0 + j]);
  if (MODE < 2) {
    const int pos = t + (MODE == 0 ? 2048 : 0);
    const float* cp = cosb + pos * 256 + d0;
    const float* sp = sinb + pos * 256 + d0;
    bf16x4 ov;
#pragma unroll
    for (int j = 0; j < 4; j++) {
      float other = __shfl_xor(n[j], 32);           // d and d^128 live in lane^32
      float rot = (lane < 32) ? -other : other;     // rotate_half sign
      float r = n[j] * cp[j] + rot * sp[j];
      if (MODE == 0) r *= 0.0625f;                  // fold HEAD_DIM^-0.5 (exact pow2)
      ov[j] = (__bf16)r;
    }
    *(bf16x4*)(row + d0) = ov;
  } else {
#pragma unroll
    for (int j = 0; j < 4; j++)
      VT[(size_t)h * (256 * 4096) + (size_t)(d0 + j) * 4096 + t] = (__bf16)n[j];
  }
}

// ---------- flash attention, fixed softmax max (softcap bounds logits to +-50) ----------
// 512 blocks; dispatcher co-locates (b, b+256) on one CU (round-robin XCD fill),
// so qt is remapped: b<256 -> qt=0..7, b>=256 -> qt=15..8. Each CU pair then does
// exactly 49 steps total regardless of b -> uniform makespan (fixes R4's 14.7%
// occupancy tail). 4 waves x 32 q-rows; double-buffered K/V LDS; normalized fp16
// partials per KV-split (R3 underflow fix).
__global__ __launch_bounds__(256, 2) void attn_kernel(
    const __bf16* __restrict__ Q,   // [2048][8*256] post norm+rope, prescaled 2^-4
    const __bf16* __restrict__ K,   // [4096][2048] cols 0..1023 = K heads (post norm+rope)
    const __bf16* __restrict__ VT,  // [4][256][4096] post norm, transposed
    _Float16* __restrict__ Op,      // [4][2048][2048] normalized partial O (fp16)
    float* __restrict__ Lp) {       // [4][2048][8]    partial l (fp32)
  __shared__ __bf16 Ksm[2][8][32][32];  // 32 KB  [buf][d-panel][key][d]
  __shared__ __bf16 Vsm[2][256][32];    // 32 KB  [buf][d][key]
  __shared__ __bf16 Pex[4][32][40];     // 10 KB  per-wave P C->A exchange
  const int tid = threadIdx.x;
  const int lane = tid & 63, wave = tid >> 6;
  const int quad = lane >> 4, l15 = lane & 15;
  const int b = blockIdx.x;
  const int idx = b & 255;
  const int h = idx & 7, sp = (idx >> 3) & 3;
  int qt = idx >> 5;                    // 0..7
  if (b >= 256) qt = 15 - qt;           // long-short pairing on co-resident CUs
  const int kvh = h >> 1;

  const int T = 68 + 4 * qt;            // total 32-key steps; T % 4 == 0 always
  const int nst = T >> 2;
  const int s0 = sp * nst;

  bf16x8 qf[2][8];
#pragma unroll
  for (int r = 0; r < 2; r++) {
    const __bf16* qp = Q + (size_t)(qt * 128 + wave * 32 + r * 16 + l15) * 2048 + h * 256 + quad * 8;
#pragma unroll
    for (int s = 0; s < 8; s++) qf[r][s] = *(const bf16x8*)(qp + s * 32);
  }
  f32x4 o[2][16];
#pragma unroll
  for (int r = 0; r < 2; r++)
#pragma unroll
    for (int i = 0; i < 16; i++) o[r][i] = (f32x4){0.f, 0.f, 0.f, 0.f};
  float rs[2][4] = {{0.f, 0.f, 0.f, 0.f}, {0.f, 0.f, 0.f, 0.f}};

  const __bf16* Kb = K + kvh * 256;
  const __bf16* Vb = VT + (size_t)kvh * (256 * 4096);
  const int rA = lane >> 2, cA = (lane & 3) * 8;
  const int qbase = 2048 + qt * 128 + wave * 32 + quad * 4;  // + r*16 + j

  // stage step s0 into buf 0
  {
    const int t0 = s0 * 32;
#pragma unroll
    for (int ch = 0; ch < 4; ch++) {
      int cc = wave + ch * 4;
      int s = cc >> 1, hf = cc & 1;
      load_lds16(Kb + (size_t)(t0 + hf * 16 + rA) * 2048 + s * 32 + cA, &Ksm[0][s][hf * 16][0]);
      load_lds16(Vb + (size_t)(cc * 16 + rA) * 4096 + t0 + cA, &Vsm[0][cc * 16][0]);
    }
  }

  for (int i = 0; i < nst; i++) {
    const int buf = i & 1;
    const int t0 = (s0 + i) * 32;
    __syncthreads();  // buf ready; all waves done with other buf
    if (i + 1 < nst) {
      const int t1 = t0 + 32;
#pragma unroll
      for (int ch = 0; ch < 4; ch++) {
        int cc = wave + ch * 4;
        int s = cc >> 1, hf = cc & 1;
        load_lds16(Kb + (size_t)(t1 + hf * 16 + rA) * 2048 + s * 32 + cA, &Ksm[buf ^ 1][s][hf * 16][0]);
        load_lds16(Vb + (size_t)(cc * 16 + rA) * 4096 + t1 + cA, &Vsm[buf ^ 1][cc * 16][0]);
      }
    }

    // S = Q K^T : 32q x 32k per wave; each K B-frag feeds 2 MFMAs (r=0,1)
    f32x4 s4[2][2];
    s4[0][0] = (f32x4){0.f, 0.f, 0.f, 0.f};
    s4[0][1] = s4[0][0]; s4[1][0] = s4[0][0]; s4[1][1] = s4[0][0];
#pragma unroll
    for (int s = 0; s < 8; s++) {
      bf16x8 b0 = *(const bf16x8*)(&Ksm[buf][s][l15][quad * 8]);
      bf16x8 b1 = *(const bf16x8*)(&Ksm[buf][s][16 + l15][quad * 8]);
      s4[0][0] = __builtin_amdgcn_mfma_f32_16x16x32_bf16(qf[0][s], b0, s4[0][0], 0, 0, 0);
      s4[0][1] = __builtin_amdgcn_mfma_f32_16x16x32_bf16(qf[0][s], b1, s4[0][1], 0, 0, 0);
      s4[1][0] = __builtin_amdgcn_mfma_f32_16x16x32_bf16(qf[1][s], b0, s4[1][0], 0, 0, 0);
      s4[1][1] = __builtin_amdgcn_mfma_f32_16x16x32_bf16(qf[1][s], b1, s4[1][1], 0, 0, 0);
    }

    // p = exp(50*tanh(v/50) - 50) = exp(-100/(e^{0.04v}+1)); max pinned at 50.
    const bool mk = (sp == 3) && (i >= nst - 4);
#pragma unroll
    for (int r = 0; r < 2; r++)
#pragma unroll
      for (int nt = 0; nt < 2; nt++) {
        const int key = t0 + nt * 16 + l15;
#pragma unroll
        for (int j = 0; j < 4; j++) {
          float v = s4[r][nt][j];
          float e = __expf(v * 0.04f);
          float p = __expf(-100.f * __builtin_amdgcn_rcpf(e + 1.f));
          if (mk && key > qbase + r * 16 + j) p = 0.f;
          s4[r][nt][j] = p;
          rs[r][j] += p;  // per-lane partial; cross-lane reduce at end
        }
      }

    // P: C-layout -> LDS -> A-layout (per-wave slab)
#pragma unroll
    for (int r = 0; r < 2; r++)
#pragma unroll
      for (int nt = 0; nt < 2; nt++)
#pragma unroll
        for (int j = 0; j < 4; j++)
          Pex[wave][r * 16 + quad * 4 + j][nt * 16 + l15] = (__bf16)s4[r][nt][j];

    bf16x8 pf0 = *(const bf16x8*)(&Pex[wave][l15][quad * 8]);
    bf16x8 pf1 = *(const bf16x8*)(&Pex[wave][16 + l15][quad * 8]);
#pragma unroll
    for (int d = 0; d < 16; d++) {
      bf16x8 vf = *(const bf16x8*)(&Vsm[buf][d * 16 + l15][quad * 8]);
      o[0][d] = __builtin_amdgcn_mfma_f32_16x16x32_bf16(pf0, vf, o[0][d], 0, 0, 0);
      o[1][d] = __builtin_amdgcn_mfma_f32_16x16x32_bf16(pf1, vf, o[1][d], 0, 0, 0);
    }
  }

  // reduce row-sums over the 16 key-columns held across l15 lanes
#pragma unroll
  for (int off = 1; off < 16; off <<= 1)
#pragma unroll
    for (int r = 0; r < 2; r++)
#pragma unroll
      for (int j = 0; j < 4; j++) rs[r][j] += __shfl_xor(rs[r][j], off);

  _Float16* Os = Op + (size_t)sp * (2048 * 2048);
  float* Ls = Lp + sp * (2048 * 8);
#pragma unroll
  for (int r = 0; r < 2; r++) {
    float inv[4];
#pragma unroll
    for (int j = 0; j < 4; j++)
      inv[j] = rs[r][j] > 0.f ? 1.f / rs[r][j] : 0.f;
    const int trow = qt * 128 + wave * 32 + r * 16 + quad * 4;
#pragma unroll
    for (int d = 0; d < 16; d++) {
      const int col = h * 256 + d * 16 + l15;
#pragma unroll
      for (int j = 0; j < 4; j++)
        Os[(size_t)(trow + j) * 2048 + col] = (_Float16)(o[r][d][j] * inv[j]);
    }
    if (l15 == 0) {
#pragma unroll
      for (int j = 0; j < 4; j++) Ls[(trow + j) * 8 + h] = rs[r][j];
    }
  }
}

// ---------- merge: O = sum(l_i * Onorm_i) / sum(l_i) ----------
__global__ void merge_kernel(const _Float16* __restrict__ Op, const float* __restrict__ Lp,
                             __bf16* __restrict__ AO) {
  int f = (blockIdx.x * 256 + threadIdx.x) * 4;
  int q = f >> 11, col = f & 2047, h = col >> 8;
  float lsum = 0.f;
  float acc[4] = {0.f, 0.f, 0.f, 0.f};
#pragma unroll
  for (int s = 0; s < 4; s++) {
    float l = Lp[s * (2048 * 8) + q * 8 + h];
    lsum += l;
    f16x4 v = *(const f16x4*)(Op + (size_t)s * (2048 * 2048) + f);
#pragma unroll
    for (int j = 0; j < 4; j++) acc[j] += l * (float)v[j];
  }
  float inv = 1.f / lsum;
  bf16x4 o;
#pragma unroll
  for (int j = 0; j < 4; j++) o[j] = (__bf16)(acc[j] * inv);
  *(bf16x4*)(AO + f) = o;
}

extern "C" void kernel_launch(void* const* d_in, const int* in_sizes, int n_in,
                              void* d_out, int out_size, void* d_ws, size_t ws_size,
                              hipStream_t stream) {
  const float* hidden = (const float*)d_in[0];
  const float* cosb = (const float*)d_in[1];
  const float* sinb = (const float*)d_in[2];
  // d_in[3] attention_mask: causal, reproduced analytically
  const float* wq = (const float*)d_in[4];
  const float* wk = (const float*)d_in[5];
  const float* wv = (const float*)d_in[6];
  const float* wo = (const float*)d_in[7];
  const float* qw = (const float*)d_in[8];
  const float* kw = (const float*)d_in[9];
  const float* vw = (const float*)d_in[10];
  float* outp = (float*)d_out;

  char* p = (char*)d_ws;
  __bf16* Xb = (__bf16*)p;   p += (size_t)SEQL * HID * 2;       // 16 MB (dead after GEMMs)
  __bf16* WQT = (__bf16*)p;  p += (size_t)2048 * 2048 * 2;      // 8 MB  (dead after Q GEMM)
  __bf16* WKVT = (__bf16*)p; p += (size_t)2048 * 2048 * 2;      // 8 MB  (dead after KV GEMM)
  __bf16* WOT = (__bf16*)p;  p += (size_t)2048 * 2048 * 2;      // 8 MB
  __bf16* Qp = (__bf16*)p;   p += (size_t)2048 * 2048 * 2;      // 8 MB
  __bf16* KVp = (__bf16*)p;  p += (size_t)4096 * 2048 * 2;      // 16 MB
  __bf16* VT = (__bf16*)p;   p += (size_t)4 * 256 * 4096 * 2;   // 8 MB
  __bf16* AO = (__bf16*)p;   p += (size_t)2048 * 2048 * 2;      // 8 MB
  float* Lpart = (float*)p;  p += (size_t)4 * 2048 * 8 * 4;     // 256 KB (total ~80.3 MB)
  // fp16 normalized partial O (4 x 8 MB = 32 MB) overlays the dead
  // Xb(16)+WQT(8)+WKVT(8) regions (contiguous, end exactly at WOT).
  _Float16* Opart = (_Float16*)Xb;

  // 1) convert inputs / weights to bf16 (weights transposed to NxK)
  cvt_bf16_kernel<<<8192, 256, 0, stream>>>(hidden, Xb);
  transpose_cvt_kernel<<<dim3(32, 32), 256, 0, stream>>>(wq, WQT, 2048, 2048);
  transpose_cvt_kernel<<<dim3(16, 32), 256, 0, stream>>>(wk, WKVT, 2048, 1024);
  transpose_cvt_kernel<<<dim3(16, 32), 256, 0, stream>>>(wv, WKVT + (size_t)1024 * 2048, 2048, 1024);
  transpose_cvt_kernel<<<dim3(32, 32), 256, 0, stream>>>(wo, WOT, 2048, 2048);

  // 2) fused Q + KV projections: 768 blocks (512 KV + 256 Q), 3 blocks/CU
  proj_kernel<<<768, 256, 0, stream>>>(Xb, WQT, WKVT, Qp, KVp);

  // 3) RMSNorm (+RoPE); Q prescaled by 2^-4; V transposed for PV fragments
  norm_rope_kernel<0><<<4096, 256, 0, stream>>>(Qp, 2048, nullptr, cosb, sinb, qw);
  norm_rope_kernel<1><<<4096, 256, 0, stream>>>(KVp, 2048, nullptr, cosb, sinb, kw);
  norm_rope_kernel<2><<<4096, 256, 0, stream>>>(KVp + 1024, 2048, VT, cosb, sinb, vw);

  // 4) flash attention, KV-split x4, load-balanced qt remap, fp16 normalized partials
  attn_kernel<<<512, 256, 0, stream>>>(Qp, KVp, VT, Opart, Lpart);
  merge_kernel<<<4096, 256, 0, stream>>>(Opart, Lpart, AO);

  // 5) output projection -> fp32 (128x64 tiles, 512 blocks)
  gemm_bt_kernel<2, true><<<dim3(16, 32), 256, 0, stream>>>(AO, WOT, outp, 2048, 2048, 2048);
}

// Round 6
// 394.211 us; speedup vs baseline: 1.2519x; 1.1503x over previous
//
#include <hip/hip_runtime.h>

// Fixed problem sizes
#define HID 2048
#define SEQL 4096
#define CHUNK 2048
#define NHEADS 8
#define NKVH 4
#define HDIM 256

typedef __bf16 bf16x4 __attribute__((ext_vector_type(4)));
typedef __bf16 bf16x8 __attribute__((ext_vector_type(8)));
typedef float f32x4 __attribute__((ext_vector_type(4)));
typedef _Float16 f16x4 __attribute__((ext_vector_type(4)));
typedef __attribute__((address_space(1))) unsigned int* as1_u32;
typedef __attribute__((address_space(3))) unsigned int* as3_u32;

// async global->LDS, 16B per lane; LDS dest = uniform base + lane*16
__device__ __forceinline__ void load_lds16(const __bf16* g, __bf16* l) {
  __builtin_amdgcn_global_load_lds((as1_u32)g, (as3_u32)l, 16, 0, 0);
}

// ---------- fp32 -> bf16 convert (4 elems/thread) ----------
__global__ void cvt_bf16_kernel(const float* __restrict__ X, __bf16* __restrict__ Y) {
  int i = blockIdx.x * blockDim.x + threadIdx.x;
  const float4* xv = (const float4*)X;
  float4 v = xv[i];
  bf16x4 o;
  o[0] = (__bf16)v.x; o[1] = (__bf16)v.y; o[2] = (__bf16)v.z; o[3] = (__bf16)v.w;
  *(bf16x4*)(Y + i * 4) = o;
}

// ---------- all 4 weights: W (RxC f32) -> WT (CxR bf16), one launch ----------
__global__ void transpose_all_kernel(const float* __restrict__ wq, const float* __restrict__ wk,
                                     const float* __restrict__ wv, const float* __restrict__ wo,
                                     __bf16* __restrict__ WQT, __bf16* __restrict__ WKVT,
                                     __bf16* __restrict__ WOT) {
  __shared__ float tile[64][65];
  const int b = blockIdx.x;
  const float* W;
  __bf16* WT;
  int R, C, bx, by;
  if (b < 1024) { W = wq; WT = WQT; R = 2048; C = 2048; bx = b & 31; by = b >> 5; }
  else if (b < 1536) { int q = b - 1024; W = wk; WT = WKVT; R = 2048; C = 1024; bx = q & 15; by = q >> 4; }
  else if (b < 2048) { int q = b - 1536; W = wv; WT = WKVT + (size_t)1024 * 2048; R = 2048; C = 1024; bx = q & 15; by = q >> 4; }
  else { int q = b - 2048; W = wo; WT = WOT; R = 2048; C = 2048; bx = q & 31; by = q >> 5; }
  int r0 = by * 64, c0 = bx * 64;
  for (int i = threadIdx.x; i < 4096; i += 256) {
    int r = i >> 6, c = i & 63;
    tile[r][c] = W[(size_t)(r0 + r) * C + c0 + c];
  }
  __syncthreads();
  for (int i = threadIdx.x; i < 4096; i += 256) {
    int c = i >> 6, r = i & 63;
    WT[(size_t)(c0 + c) * R + r0 + r] = (__bf16)tile[r][c];
  }
}

// ---------- fused Q + KV projection: 768 blocks, all 128x128 tiles, 3 blocks/CU ----------
__global__ __launch_bounds__(256, 3) void proj_kernel(
    const __bf16* __restrict__ Xb, const __bf16* __restrict__ WQT,
    const __bf16* __restrict__ WKVT, __bf16* __restrict__ Qp, __bf16* __restrict__ KVp) {
  __shared__ __bf16 Asm[128 * 32];
  __shared__ __bf16 Bsm[128 * 32];
  const int tid = threadIdx.x;
  const int lane = tid & 63, wave = tid >> 6;
  const int quad = lane >> 4, l15 = lane & 15;
  const int b = blockIdx.x;
  const __bf16 *A, *B;
  __bf16* C;
  int m0, n0;
  if (b < 512) {
    A = Xb; B = WKVT; C = KVp;
    m0 = (b & 31) * 128; n0 = (b >> 5) * 128;
  } else {
    int q = b - 512;
    A = Xb + (size_t)2048 * 2048; B = WQT; C = Qp;
    m0 = (q & 15) * 128; n0 = (q >> 4) * 128;
  }
  const int wm = (wave & 1) * 64, wn = (wave >> 1) * 64;
  f32x4 acc[4][4];
#pragma unroll
  for (int i = 0; i < 4; i++)
#pragma unroll
    for (int j = 0; j < 4; j++) acc[i][j] = (f32x4){0.f, 0.f, 0.f, 0.f};

  const int rA = lane >> 2, cA = (lane & 3) * 8;

  for (int k0 = 0; k0 < 2048; k0 += 32) {
#pragma unroll
    for (int c = wave; c < 8; c += 4) {
      load_lds16(A + (size_t)(m0 + c * 16 + rA) * 2048 + k0 + cA, Asm + c * 512);
      load_lds16(B + (size_t)(n0 + c * 16 + rA) * 2048 + k0 + cA, Bsm + c * 512);
    }
    __syncthreads();
    bf16x8 af[4], bfr[4];
#pragma unroll
    for (int i = 0; i < 4; i++) {
      af[i] = *(const bf16x8*)(Asm + (wm + i * 16 + l15) * 32 + quad * 8);
      bfr[i] = *(const bf16x8*)(Bsm + (wn + i * 16 + l15) * 32 + quad * 8);
    }
#pragma unroll
    for (int mi = 0; mi < 4; mi++)
#pragma unroll
      for (int ni = 0; ni < 4; ni++)
        acc[mi][ni] = __builtin_amdgcn_mfma_f32_16x16x32_bf16(af[mi], bfr[ni], acc[mi][ni], 0, 0, 0);
    __syncthreads();
  }
#pragma unroll
  for (int mi = 0; mi < 4; mi++) {
    int r = m0 + wm + mi * 16 + quad * 4;
#pragma unroll
    for (int ni = 0; ni < 4; ni++) {
      int cc = n0 + wn + ni * 16 + l15;
#pragma unroll
      for (int j = 0; j < 4; j++)
        C[(size_t)(r + j) * 2048 + cc] = (__bf16)acc[mi][ni][j];
    }
  }
}

// ---------- C(MxN) = A(MxK) @ B^T(NxK), bf16 in, fp32 acc (output projection) ----------
template <int NI, bool F32OUT>
__global__ __launch_bounds__(256, 2) void gemm_bt_kernel(
    const __bf16* __restrict__ A, const __bf16* __restrict__ B,
    void* __restrict__ Cv, int M, int N, int Kd) {
  constexpr int BN = NI * 32;
  __shared__ __bf16 Asm[128 * 32];
  __shared__ __bf16 Bsm[BN * 32];
  const int tid = threadIdx.x;
  const int lane = tid & 63, wave = tid >> 6;
  const int quad = lane >> 4, l15 = lane & 15;
  const int m0 = blockIdx.x * 128, n0 = blockIdx.y * BN;
  const int wm = (wave & 1) * 64, wn = (wave >> 1) * (NI * 16);
  f32x4 acc[4][NI];
#pragma unroll
  for (int i = 0; i < 4; i++)
#pragma unroll
    for (int j = 0; j < NI; j++) acc[i][j] = (f32x4){0.f, 0.f, 0.f, 0.f};

  const int rA = lane >> 2, cA = (lane & 3) * 8;

  for (int k0 = 0; k0 < Kd; k0 += 32) {
#pragma unroll
    for (int c = wave; c < 8; c += 4)
      load_lds16(A + (size_t)(m0 + c * 16 + rA) * Kd + k0 + cA, Asm + c * 512);
#pragma unroll
    for (int c = wave; c < BN / 16; c += 4)
      load_lds16(B + (size_t)(n0 + c * 16 + rA) * Kd + k0 + cA, Bsm + c * 512);
    __syncthreads();
    bf16x8 af[4], bfr[NI];
#pragma unroll
    for (int i = 0; i < 4; i++)
      af[i] = *(const bf16x8*)(Asm + (wm + i * 16 + l15) * 32 + quad * 8);
#pragma unroll
    for (int i = 0; i < NI; i++)
      bfr[i] = *(const bf16x8*)(Bsm + (wn + i * 16 + l15) * 32 + quad * 8);
#pragma unroll
    for (int mi = 0; mi < 4; mi++)
#pragma unroll
      for (int ni = 0; ni < NI; ni++)
        acc[mi][ni] = __builtin_amdgcn_mfma_f32_16x16x32_bf16(af[mi], bfr[ni], acc[mi][ni], 0, 0, 0);
    __syncthreads();
  }
#pragma unroll
  for (int mi = 0; mi < 4; mi++) {
    int r = m0 + wm + mi * 16 + quad * 4;
#pragma unroll
    for (int ni = 0; ni < NI; ni++) {
      int cc = n0 + wn + ni * 16 + l15;
#pragma unroll
      for (int j = 0; j < 4; j++) {
        if (F32OUT)
          ((float*)Cv)[(size_t)(r + j) * N + cc] = acc[mi][ni][j];
        else
          ((__bf16*)Cv)[(size_t)(r + j) * N + cc] = (__bf16)acc[mi][ni][j];
      }
    }
  }
}

// ---------- unified RMSNorm (+RoPE) for Q, K, V in one launch ----------
// wave id gw: [0,16384) -> Q rows (t,h), rope pos t+2048, prescale 2^-4
//             [16384,49152) -> KV rows: r<4 = K head (rope pos t), r>=4 = V head (->VT)
__global__ void norm_all_kernel(__bf16* __restrict__ Qp, __bf16* __restrict__ KVp,
                                __bf16* __restrict__ VT,
                                const float* __restrict__ cosb, const float* __restrict__ sinb,
                                const float* __restrict__ qw, const float* __restrict__ kw,
                                const float* __restrict__ vw) {
  const int gw = (blockIdx.x * 256 + threadIdx.x) >> 6;
  const int lane = threadIdx.x & 63;
  const int d0 = lane * 4;

  __bf16* row;
  const float* w;
  int pos = -1;            // -1: no rope (V)
  int vh = 0, vt = 0;
  bool isV = false;
  float prescale = 1.f;
  if (gw < 16384) {
    int t = gw >> 3, h = gw & 7;
    row = Qp + (size_t)t * 2048 + h * 256;
    w = qw; pos = t + 2048; prescale = 0.0625f;
  } else {
    int g2 = gw - 16384;
    int t = g2 >> 3, r = g2 & 7;
    if (r < 4) {
      row = KVp + (size_t)t * 2048 + r * 256;
      w = kw; pos = t;
    } else {
      row = KVp + (size_t)t * 2048 + 1024 + (r - 4) * 256;
      w = vw; isV = true; vh = r - 4; vt = t;
    }
  }

  bf16x4 rv = *(const bf16x4*)(row + d0);
  float x[4];
  float ss = 0.f;
#pragma unroll
  for (int j = 0; j < 4; j++) { x[j] = (float)rv[j]; ss += x[j] * x[j]; }
#pragma unroll
  for (int off = 1; off < 64; off <<= 1) ss += __shfl_xor(ss, off);
  float scale = rsqrtf(ss * (1.f / 256.f) + 1e-6f);
  float n[4];
#pragma unroll
  for (int j = 0; j < 4; j++) n[j] = x[j] * scale * (1.f + w[d0 + j]);

  if (!isV) {
    const float* cp = cosb + (size_t)pos * 256 + d0;
    const float* sp = sinb + (size_t)pos * 256 + d0;
    bf16x4 ov;
#pragma unroll
    for (int j = 0; j < 4; j++) {
      float other = __shfl_xor(n[j], 32);           // d and d^128 live in lane^32
      float rot = (lane < 32) ? -other : other;     // rotate_half sign
      ov[j] = (__bf16)((n[j] * cp[j] + rot * sp[j]) * prescale);
    }
    *(bf16x4*)(row + d0) = ov;
  } else {
#pragma unroll
    for (int j = 0; j < 4; j++)
      VT[(size_t)vh * (256 * 4096) + (size_t)(d0 + j) * 4096 + vt] = (__bf16)n[j];
  }
}

// ---------- flash attention, fixed softmax max (softcap bounds logits to +-50) ----------
// 512 blocks; (b, b+256) co-reside on a CU -> qt remap pairs long+short tiles (49 steps/CU).
// KV-split x4 is INTERLEAVED: sp processes steps s = 4i+sp (t0=(4i+sp)*32), so all
// resident blocks on an XCD walk the same ~128-key window together -> K/V stays L2-hot
// (R5: contiguous ranges gave 6 MB/XCD working set > 4 MB L2 -> L3-latency bound).
// Causal mask: each sp's LAST step is its diagonal step (s=T-4+sp).
__global__ __launch_bounds__(256, 2) void attn_kernel(
    const __bf16* __restrict__ Q,   // [2048][8*256] post norm+rope, prescaled 2^-4
    const __bf16* __restrict__ K,   // [4096][2048] cols 0..1023 = K heads (post norm+rope)
    const __bf16* __restrict__ VT,  // [4][256][4096] post norm, transposed
    _Float16* __restrict__ Op,      // [4][2048][2048] normalized partial O (fp16)
    float* __restrict__ Lp) {       // [4][2048][8]    partial l (fp32)
  __shared__ __bf16 Ksm[2][8][32][32];  // 32 KB  [buf][d-panel][key][d]
  __shared__ __bf16 Vsm[2][256][32];    // 32 KB  [buf][d][key]
  __shared__ __bf16 Pex[4][32][40];     // 10 KB  per-wave P C->A exchange
  const int tid = threadIdx.x;
  const int lane = tid & 63, wave = tid >> 6;
  const int quad = lane >> 4, l15 = lane & 15;
  const int b = blockIdx.x;
  const int idx = b & 255;
  const int h = idx & 7, sp = (idx >> 3) & 3;
  int qt = idx >> 5;                    // 0..7
  if (b >= 256) qt = 15 - qt;           // long-short pairing on co-resident CUs
  const int kvh = h >> 1;

  const int T = 68 + 4 * qt;            // total 32-key steps; T % 4 == 0 always
  const int nst = T >> 2;               // this split handles s = sp, sp+4, ..., T-4+sp

  bf16x8 qf[2][8];
#pragma unroll
  for (int r = 0; r < 2; r++) {
    const __bf16* qp = Q + (size_t)(qt * 128 + wave * 32 + r * 16 + l15) * 2048 + h * 256 + quad * 8;
#pragma unroll
    for (int s = 0; s < 8; s++) qf[r][s] = *(const bf16x8*)(qp + s * 32);
  }
  f32x4 o[2][16];
#pragma unroll
  for (int r = 0; r < 2; r++)
#pragma unroll
    for (int i = 0; i < 16; i++) o[r][i] = (f32x4){0.f, 0.f, 0.f, 0.f};
  float rs[2][4] = {{0.f, 0.f, 0.f, 0.f}, {0.f, 0.f, 0.f, 0.f}};

  const __bf16* Kb = K + kvh * 256;
  const __bf16* Vb = VT + (size_t)kvh * (256 * 4096);
  const int rA = lane >> 2, cA = (lane & 3) * 8;
  const int qbase = 2048 + qt * 128 + wave * 32 + quad * 4;  // + r*16 + j

  // stage step s=sp into buf 0
  {
    const int t0 = sp * 32;
#pragma unroll
    for (int ch = 0; ch < 4; ch++) {
      int cc = wave + ch * 4;
      int s = cc >> 1, hf = cc & 1;
      load_lds16(Kb + (size_t)(t0 + hf * 16 + rA) * 2048 + s * 32 + cA, &Ksm[0][s][hf * 16][0]);
      load_lds16(Vb + (size_t)(cc * 16 + rA) * 4096 + t0 + cA, &Vsm[0][cc * 16][0]);
    }
  }

  for (int i = 0; i < nst; i++) {
    const int buf = i & 1;
    const int t0 = (4 * i + sp) * 32;
    __syncthreads();  // buf ready; all waves done with other buf
    if (i + 1 < nst) {
      const int t1 = t0 + 128;
#pragma unroll
      for (int ch = 0; ch < 4; ch++) {
        int cc = wave + ch * 4;
        int s = cc >> 1, hf = cc & 1;
        load_lds16(Kb + (size_t)(t1 + hf * 16 + rA) * 2048 + s * 32 + cA, &Ksm[buf ^ 1][s][hf * 16][0]);
        load_lds16(Vb + (size_t)(cc * 16 + rA) * 4096 + t1 + cA, &Vsm[buf ^ 1][cc * 16][0]);
      }
    }

    // S = Q K^T : 32q x 32k per wave; each K B-frag feeds 2 MFMAs (r=0,1)
    f32x4 s4[2][2];
    s4[0][0] = (f32x4){0.f, 0.f, 0.f, 0.f};
    s4[0][1] = s4[0][0]; s4[1][0] = s4[0][0]; s4[1][1] = s4[0][0];
#pragma unroll
    for (int s = 0; s < 8; s++) {
      bf16x8 b0 = *(const bf16x8*)(&Ksm[buf][s][l15][quad * 8]);
      bf16x8 b1 = *(const bf16x8*)(&Ksm[buf][s][16 + l15][quad * 8]);
      s4[0][0] = __builtin_amdgcn_mfma_f32_16x16x32_bf16(qf[0][s], b0, s4[0][0], 0, 0, 0);
      s4[0][1] = __builtin_amdgcn_mfma_f32_16x16x32_bf16(qf[0][s], b1, s4[0][1], 0, 0, 0);
      s4[1][0] = __builtin_amdgcn_mfma_f32_16x16x32_bf16(qf[1][s], b0, s4[1][0], 0, 0, 0);
      s4[1][1] = __builtin_amdgcn_mfma_f32_16x16x32_bf16(qf[1][s], b1, s4[1][1], 0, 0, 0);
    }

    // p = exp(50*tanh(v/50) - 50) = exp(-100/(e^{0.04v}+1)); max pinned at 50.
    const bool mk = (i == nst - 1);     // diagonal step for this sp
#pragma unroll
    for (int r = 0; r < 2; r++)
#pragma unroll
      for (int nt = 0; nt < 2; nt++) {
        const int key = t0 + nt * 16 + l15;
#pragma unroll
        for (int j = 0; j < 4; j++) {
          float v = s4[r][nt][j];
          float e = __expf(v * 0.04f);
          float p = __expf(-100.f * __builtin_amdgcn_rcpf(e + 1.f));
          if (mk && key > qbase + r * 16 + j) p = 0.f;
          s4[r][nt][j] = p;
          rs[r][j] += p;  // per-lane partial; cross-lane reduce at end
        }
      }

    // P: C-layout -> LDS -> A-layout (per-wave slab)
#pragma unroll
    for (int r = 0; r < 2; r++)
#pragma unroll
      for (int nt = 0; nt < 2; nt++)
#pragma unroll
        for (int j = 0; j < 4; j++)
          Pex[wave][r * 16 + quad * 4 + j][nt * 16 + l15] = (__bf16)s4[r][nt][j];

    bf16x8 pf0 = *(const bf16x8*)(&Pex[wave][l15][quad * 8]);
    bf16x8 pf1 = *(const bf16x8*)(&Pex[wave][16 + l15][quad * 8]);
#pragma unroll
    for (int d = 0; d < 16; d++) {
      bf16x8 vf = *(const bf16x8*)(&Vsm[buf][d * 16 + l15][quad * 8]);
      o[0][d] = __builtin_amdgcn_mfma_f32_16x16x32_bf16(pf0, vf, o[0][d], 0, 0, 0);
      o[1][d] = __builtin_amdgcn_mfma_f32_16x16x32_bf16(pf1, vf, o[1][d], 0, 0, 0);
    }
  }

  // reduce row-sums over the 16 key-columns held across l15 lanes
#pragma unroll
  for (int off = 1; off < 16; off <<= 1)
#pragma unroll
    for (int r = 0; r < 2; r++)
#pragma unroll
      for (int j = 0; j < 4; j++) rs[r][j] += __shfl_xor(rs[r][j], off);

  _Float16* Os = Op + (size_t)sp * (2048 * 2048);
  float* Ls = Lp + sp * (2048 * 8);
#pragma unroll
  for (int r = 0; r < 2; r++) {
    float inv[4];
#pragma unroll
    for (int j = 0; j < 4; j++)
      inv[j] = rs[r][j] > 0.f ? 1.f / rs[r][j] : 0.f;
    const int trow = qt * 128 + wave * 32 + r * 16 + quad * 4;
#pragma unroll
    for (int d = 0; d < 16; d++) {
      const int col = h * 256 + d * 16 + l15;
#pragma unroll
      for (int j = 0; j < 4; j++)
        Os[(size_t)(trow + j) * 2048 + col] = (_Float16)(o[r][d][j] * inv[j]);
    }
    if (l15 == 0) {
#pragma unroll
      for (int j = 0; j < 4; j++) Ls[(trow + j) * 8 + h] = rs[r][j];
    }
  }
}

// ---------- merge: O = sum(l_i * Onorm_i) / sum(l_i) ----------
__global__ void merge_kernel(const _Float16* __restrict__ Op, const float* __restrict__ Lp,
                             __bf16* __restrict__ AO) {
  int f = (blockIdx.x * 256 + threadIdx.x) * 4;
  int q = f >> 11, col = f & 2047, h = col >> 8;
  float lsum = 0.f;
  float acc[4] = {0.f, 0.f, 0.f, 0.f};
#pragma unroll
  for (int s = 0; s < 4; s++) {
    float l = Lp[s * (2048 * 8) + q * 8 + h];
    lsum += l;
    f16x4 v = *(const f16x4*)(Op + (size_t)s * (2048 * 2048) + f);
#pragma unroll
    for (int j = 0; j < 4; j++) acc[j] += l * (float)v[j];
  }
  float inv = 1.f / lsum;
  bf16x4 o;
#pragma unroll
  for (int j = 0; j < 4; j++) o[j] = (__bf16)(acc[j] * inv);
  *(bf16x4*)(AO + f) = o;
}

extern "C" void kernel_launch(void* const* d_in, const int* in_sizes, int n_in,
                              void* d_out, int out_size, void* d_ws, size_t ws_size,
                              hipStream_t stream) {
  const float* hidden = (const float*)d_in[0];
  const float* cosb = (const float*)d_in[1];
  const float* sinb = (const float*)d_in[2];
  // d_in[3] attention_mask: causal, reproduced analytically
  const float* wq = (const float*)d_in[4];
  const float* wk = (const float*)d_in[5];
  const float* wv = (const float*)d_in[6];
  const float* wo = (const float*)d_in[7];
  const float* qw = (const float*)d_in[8];
  const float* kw = (const float*)d_in[9];
  const float* vw = (const float*)d_in[10];
  float* outp = (float*)d_out;

  char* p = (char*)d_ws;
  __bf16* Xb = (__bf16*)p;   p += (size_t)SEQL * HID * 2;       // 16 MB (dead after GEMMs)
  __bf16* WQT = (__bf16*)p;  p += (size_t)2048 * 2048 * 2;      // 8 MB  (dead after Q GEMM)
  __bf16* WKVT = (__bf16*)p; p += (size_t)2048 * 2048 * 2;      // 8 MB  (dead after KV GEMM)
  __bf16* WOT = (__bf16*)p;  p += (size_t)2048 * 2048 * 2;      // 8 MB
  __bf16* Qp = (__bf16*)p;   p += (size_t)2048 * 2048 * 2;      // 8 MB
  __bf16* KVp = (__bf16*)p;  p += (size_t)4096 * 2048 * 2;      // 16 MB
  __bf16* VT = (__bf16*)p;   p += (size_t)4 * 256 * 4096 * 2;   // 8 MB
  __bf16* AO = (__bf16*)p;   p += (size_t)2048 * 2048 * 2;      // 8 MB
  float* Lpart = (float*)p;  p += (size_t)4 * 2048 * 8 * 4;     // 256 KB (total ~80.3 MB)
  // fp16 normalized partial O (4 x 8 MB = 32 MB) overlays the dead
  // Xb(16)+WQT(8)+WKVT(8) regions (contiguous, end exactly at WOT).
  _Float16* Opart = (_Float16*)Xb;

  // 1) convert input to bf16; all weight transposes fused into one launch
  cvt_bf16_kernel<<<8192, 256, 0, stream>>>(hidden, Xb);
  transpose_all_kernel<<<3072, 256, 0, stream>>>(wq, wk, wv, wo, WQT, WKVT, WOT);

  // 2) fused Q + KV projections: 768 blocks (512 KV + 256 Q), 3 blocks/CU
  proj_kernel<<<768, 256, 0, stream>>>(Xb, WQT, WKVT, Qp, KVp);

  // 3) unified RMSNorm (+RoPE) for Q, K, V in one launch (12288 blocks)
  norm_all_kernel<<<12288, 256, 0, stream>>>(Qp, KVp, VT, cosb, sinb, qw, kw, vw);

  // 4) flash attention, interleaved KV-split x4 (L2-hot), fp16 normalized partials
  attn_kernel<<<512, 256, 0, stream>>>(Qp, KVp, VT, Opart, Lpart);
  merge_kernel<<<4096, 256, 0, stream>>>(Opart, Lpart, AO);

  // 5) output projection -> fp32 (128x64 tiles, 512 blocks)
  gemm_bt_kernel<2, true><<<dim3(16, 32), 256, 0, stream>>>(AO, WOT, outp, 2048, 2048, 2048);
}